// Round 11
// baseline (236.584 us; speedup 1.0000x reference)
//
#include <hip/hip_runtime.h>
#include <hip/hip_bf16.h>
#include <cstdint>

// Net_79139067396690: MC-dropout moment-propagation MLP.
//   h   = relu(0.5*x@W1^T + 0.5*sqrt((x^2)@(W1^2)^T) * eps1/sqrt(1000))
//   out =      0.5*h@W2^T + 0.5*sqrt((h^2)@(W2^2)^T) * eps2/sqrt(1000)
// Round 11: BARRIER-FREE gemm1. r8-r10 signature (all pipes idle, models 5-10x
// off) matches m233's "2-barrier-per-K-step scaffolding = ~72% overhead".
// A-frags are 8 contiguous f32/lane -> load straight from x (L1-shared within
// block), cvt in-reg, zero LDS, zero __syncthreads in the K-loop. 16 waves/CU
// stream independently. Layer2/packs = r9. All reg state NAMED (rule #20).

#define K_DIM 784
#define KP 800                 // K padded to multiple of 32 in the W1 pack
#define N_HID 256
#define N_OUT 10
#define NSTEP 25               // KP/32
#define WSQ_OFF (N_HID * KP)   // u16 offset of squared-W1 pack
#define W2_OFF (832 * 1024)    // byte offset of W2 pack in d_ws
#define W2SQ 4096              // u16 offset of squared-W2 pack
#define H_OFF (1 << 20)        // byte offset of h in d_ws
#define BM2 128                // layer2 rows per block

using short8 = __attribute__((ext_vector_type(8))) short;
using floatx4 = __attribute__((ext_vector_type(4))) float;
typedef uint16_t u16;

// ---- Threefry-2x32 (JAX-compatible) ----
__host__ __device__ inline void threefry2x32(uint32_t k0, uint32_t k1,
                                             uint32_t x0, uint32_t x1,
                                             uint32_t& o0, uint32_t& o1) {
  uint32_t ks0 = k0, ks1 = k1, ks2 = k0 ^ k1 ^ 0x1BD11BDAu;
  x0 += ks0;
  x1 += ks1;
#define TFR(r) { x0 += x1; x1 = (x1 << (r)) | (x1 >> (32 - (r))); x1 ^= x0; }
  TFR(13) TFR(15) TFR(26) TFR(6)   x0 += ks1; x1 += ks2 + 1u;
  TFR(17) TFR(29) TFR(16) TFR(24)  x0 += ks2; x1 += ks0 + 2u;
  TFR(13) TFR(15) TFR(26) TFR(6)   x0 += ks0; x1 += ks1 + 3u;
  TFR(17) TFR(29) TFR(16) TFR(24)  x0 += ks1; x1 += ks2 + 4u;
  TFR(13) TFR(15) TFR(26) TFR(6)   x0 += ks2; x1 += ks0 + 5u;
#undef TFR
  o0 = x0;
  o1 = x1;
}

// bits -> N(0,1) ~= jax.random.normal (mantissa-uniform + Giles erfinv).
__device__ __forceinline__ float bits_to_normal(uint32_t bits) {
  const float lo = -0.99999994f;  // nextafterf(-1,0)
  float u01 = __uint_as_float((bits >> 9) | 0x3F800000u) - 1.0f;
  float u = fmaxf(lo, u01 * 2.0f + lo);
  float w = -__logf((1.0f - u) * (1.0f + u));
  float p;
  if (w < 5.0f) {
    w -= 2.5f;
    p = 2.81022636e-08f;
    p = fmaf(p, w, 3.43273939e-07f);
    p = fmaf(p, w, -3.5233877e-06f);
    p = fmaf(p, w, -4.39150654e-06f);
    p = fmaf(p, w, 0.00021858087f);
    p = fmaf(p, w, -0.00125372503f);
    p = fmaf(p, w, -0.00417768164f);
    p = fmaf(p, w, 0.246640727f);
    p = fmaf(p, w, 1.50140941f);
  } else {
    w = sqrtf(w) - 3.0f;
    p = -0.000200214257f;
    p = fmaf(p, w, 0.000100950558f);
    p = fmaf(p, w, 0.00134934322f);
    p = fmaf(p, w, -0.00367342844f);
    p = fmaf(p, w, 0.00573950773f);
    p = fmaf(p, w, -0.0076224613f);
    p = fmaf(p, w, 0.00943887047f);
    p = fmaf(p, w, 1.00167406f);
    p = fmaf(p, w, 2.83297682f);
  }
  return 1.41421356f * (p * u);
}

__device__ __forceinline__ float eps_part(uint32_t ka, uint32_t kb, uint32_t i) {
  uint32_t o0, o1;
  threefry2x32(ka, kb, 0u, i, o0, o1);
  return bits_to_normal(o0 ^ o1);
}

// f32 -> bf16 via hw cvt (RNE)
__device__ __forceinline__ u16 cvt_bf16(float f) {
  union { __hip_bfloat16 h; u16 u; } c;
  c.h = __float2bfloat16(f);
  return c.u;
}

__device__ __forceinline__ float bf2f(u16 b) {
  return __uint_as_float((uint32_t)b << 16);
}

// ---- pre-pack W1 -> bf16 {w, w^2}, K padded to 800 with zeros ----
__global__ __launch_bounds__(256) void pack_w1(const float* __restrict__ W1,
                                               u16* __restrict__ bp) {
  const int col = blockIdx.x;  // 0..255
  for (int k = threadIdx.x; k < KP; k += 256) {
    float w = (k < K_DIM) ? W1[col * K_DIM + k] : 0.0f;
    bp[col * KP + k] = cvt_bf16(w);
    bp[WSQ_OFF + col * KP + k] = cvt_bf16(w * w);
  }
}

// ---- pre-pack W2 -> bf16 {w, w^2}, cols padded 10->16 with zeros ----
__global__ __launch_bounds__(256) void pack_w2(const float* __restrict__ W2,
                                               u16* __restrict__ w2p) {
#pragma unroll
  for (int i = 0; i < 16; ++i) {
    int g = threadIdx.x + i * 256;  // 4096 = 16*256
    int col = g >> 8, k = g & 255;
    float w = (col < N_OUT) ? W2[col * N_HID + k] : 0.0f;
    w2p[g] = cvt_bf16(w);
    w2p[W2SQ + g] = cvt_bf16(w * w);
  }
}

// ---- GEMM1 + eps1 + relu -> h (bf16, global). ZERO LDS, ZERO barriers. ----
// Block: 256 thr = 4 waves; 64 rows x 128 cols; wave = 64 x 32.
// Grid: 1024 row-tiles x 2 col-tiles = 2048 blocks.
__global__ __launch_bounds__(256, 4) void gemm1(
    const float* __restrict__ x, const u16* __restrict__ bp,
    u16* __restrict__ hws, uint32_t k1a, uint32_t k1b) {
  const int tid = threadIdx.x;
  const int lane = tid & 63;
  const int l15 = lane & 15;
  const int lhal = lane >> 4;      // 0..3
  const int wn = tid >> 6;         // wave id 0..3 -> 32-col strip
  const int bid = blockIdx.x;
  const int gr0 = (bid >> 1) * 64;        // row origin
  const int bc0 = (bid & 1) * 128;        // col origin

  // B offsets (u16 units) for this wave's two 16-col fragments
  const uint32_t boff0 = (uint32_t)(bc0 + wn * 32 + l15) * KP + (uint32_t)lhal * 8;
  const uint32_t boff1 = boff0 + 16u * KP;

  // A row pointers: lane reads row (i*16 + l15), k-chunk lhal*8 (+ kk)
  const float* ax0 = x + (size_t)(gr0 + l15) * K_DIM + lhal * 8;
  const float* ax1 = ax0 + 16 * K_DIM;
  const float* ax2 = ax0 + 32 * K_DIM;
  const float* ax3 = ax0 + 48 * K_DIM;

  // NAMED accumulators: am{i}{j}, av{i}{j}, i=0..3, j=0..1
#define DECL_ACC(i) \
  floatx4 am##i##0 = {0.f, 0.f, 0.f, 0.f}, am##i##1 = {0.f, 0.f, 0.f, 0.f}; \
  floatx4 av##i##0 = {0.f, 0.f, 0.f, 0.f}, av##i##1 = {0.f, 0.f, 0.f, 0.f};
  DECL_ACC(0) DECL_ACC(1) DECL_ACC(2) DECL_ACC(3)
#undef DECL_ACC

  for (int s = 0; s < NSTEP; ++s) {
    const int kk = s * 32;
    // this wave's k-chunk validity (uniform within 16-lane group; 8-aligned)
    const bool ok = (kk + lhal * 8) < K_DIM;

    // B for this step (L2-resident 819 KB pack)
    const u16* bpk = bp + kk;
    const short8 bm0 = *reinterpret_cast<const short8*>(&bpk[boff0]);
    const short8 bm1 = *reinterpret_cast<const short8*>(&bpk[boff1]);
    const short8 bv0 = *reinterpret_cast<const short8*>(&bpk[WSQ_OFF + boff0]);
    const short8 bv1 = *reinterpret_cast<const short8*>(&bpk[WSQ_OFF + boff1]);

    // per-frag: direct global A load (L1-shared across the block's 4 waves),
    // in-register cvt to bf16 {x, x^2}, then 4 MFMAs
#define FRAG(i) { \
    float4 p0_, p1_; \
    if (ok) { \
      p0_ = *reinterpret_cast<const float4*>(ax##i + kk); \
      p1_ = *reinterpret_cast<const float4*>(ax##i + kk + 4); \
    } else { \
      p0_ = make_float4(0.f, 0.f, 0.f, 0.f); \
      p1_ = make_float4(0.f, 0.f, 0.f, 0.f); \
    } \
    short8 af_, ag_; \
    af_[0] = (short)cvt_bf16(p0_.x); ag_[0] = (short)cvt_bf16(p0_.x * p0_.x); \
    af_[1] = (short)cvt_bf16(p0_.y); ag_[1] = (short)cvt_bf16(p0_.y * p0_.y); \
    af_[2] = (short)cvt_bf16(p0_.z); ag_[2] = (short)cvt_bf16(p0_.z * p0_.z); \
    af_[3] = (short)cvt_bf16(p0_.w); ag_[3] = (short)cvt_bf16(p0_.w * p0_.w); \
    af_[4] = (short)cvt_bf16(p1_.x); ag_[4] = (short)cvt_bf16(p1_.x * p1_.x); \
    af_[5] = (short)cvt_bf16(p1_.y); ag_[5] = (short)cvt_bf16(p1_.y * p1_.y); \
    af_[6] = (short)cvt_bf16(p1_.z); ag_[6] = (short)cvt_bf16(p1_.z * p1_.z); \
    af_[7] = (short)cvt_bf16(p1_.w); ag_[7] = (short)cvt_bf16(p1_.w * p1_.w); \
    am##i##0 = __builtin_amdgcn_mfma_f32_16x16x32_bf16(af_, bm0, am##i##0, 0, 0, 0); \
    av##i##0 = __builtin_amdgcn_mfma_f32_16x16x32_bf16(ag_, bv0, av##i##0, 0, 0, 0); \
    am##i##1 = __builtin_amdgcn_mfma_f32_16x16x32_bf16(af_, bm1, am##i##1, 0, 0, 0); \
    av##i##1 = __builtin_amdgcn_mfma_f32_16x16x32_bf16(ag_, bv1, av##i##1, 0, 0, 0); }
    FRAG(0) FRAG(1) FRAG(2) FRAG(3)
#undef FRAG
  }

  // epilogue: eps1 + relu -> h (bf16) in global ws
  const float INV = 0.031622776601683794f;  // 1/sqrt(1000)
#define EPIG(AM, AV, G, I, J) do { \
    const int rl_ = I * 16 + lhal * 4 + (G); \
    const int c_ = bc0 + wn * 32 + J * 16 + l15; \
    float mean_ = 0.5f * (AM)[G]; \
    float sd_ = 0.5f * sqrtf((AV)[G]); \
    uint32_t idx_ = (uint32_t)(gr0 + rl_) * 256u + (uint32_t)c_; \
    float eps_ = eps_part(k1a, k1b, idx_); \
    float h_ = fmaxf(mean_ + sd_ * (eps_ * INV), 0.0f); \
    hws[(size_t)(gr0 + rl_) * 256 + c_] = cvt_bf16(h_); \
  } while (0)
#define EPI(i, j) do { \
    EPIG(am##i##j, av##i##j, 0, i, j); \
    EPIG(am##i##j, av##i##j, 1, i, j); \
    EPIG(am##i##j, av##i##j, 2, i, j); \
    EPIG(am##i##j, av##i##j, 3, i, j); \
  } while (0)
  EPI(0, 0); EPI(0, 1); EPI(1, 0); EPI(1, 1);
  EPI(2, 0); EPI(2, 1); EPI(3, 0); EPI(3, 1);
#undef EPI
#undef EPIG
}

// ---- layer 2 on MFMA: out = 0.5*h@W2^T + 0.5*sqrt((h^2)@(W2^2)^T)*eps2/sqrt(Z)
// Block: 256 thr = 4 waves; BM2=128 rows; wave = 32 rows x 16 cols; K=256.
__global__ __launch_bounds__(256, 4) void layer2(
    const u16* __restrict__ hws, const u16* __restrict__ w2p,
    float* __restrict__ out, uint32_t k2a, uint32_t k2b) {
  __shared__ u16 sH[2][BM2 * 32];  // [h, h^2][swizzled row*32+k] 16KB

  const int tid = threadIdx.x;
  const int lane = tid & 63;
  const int l15 = lane & 15;
  const int lhal = lane >> 4;  // 0..3
  const int wv = tid >> 6;     // wave 0..3 -> rows wv*32..wv*32+31
  const int gr0 = blockIdx.x * BM2;

  // staging: thread -> row = tid>>1, 16-u16 half = tid&1 (32B/thread coalesced)
  const int srow = tid >> 1;
  const int sq = (tid & 1) * 16;
  const u16* hrow = hws + (size_t)(gr0 + srow) * 256 + sq;
  const int sidx0 = (srow * 32 + sq) ^ ((srow & 7) << 3);
  const int sidx1 = (srow * 32 + sq + 8) ^ ((srow & 7) << 3);

  // B offsets (u16): col = l15, kgroup = lhal
  const uint32_t boff = (uint32_t)l15 * 256 + (uint32_t)lhal * 8;

  // A fragment LDS indices: rows wv*32 + i*16 + l15
#define AIDX2(i) ((((wv * 32 + i * 16 + l15) * 32 + lhal * 8)) ^ ((l15 & 7) << 3))
  const int aidx0 = AIDX2(0);
  const int aidx1 = AIDX2(1);
#undef AIDX2

  floatx4 am0 = {0.f, 0.f, 0.f, 0.f}, am1 = {0.f, 0.f, 0.f, 0.f};
  floatx4 av0 = {0.f, 0.f, 0.f, 0.f}, av1 = {0.f, 0.f, 0.f, 0.f};

  for (int s = 0; s < 8; ++s) {
    __syncthreads();  // prev-step readers done before overwrite
    const short8 c0 = *reinterpret_cast<const short8*>(&hrow[s * 32]);
    const short8 c1 = *reinterpret_cast<const short8*>(&hrow[s * 32 + 8]);
    short8 s0, s1;
#define SQE(D, S, E) { const float f_ = bf2f((u16)(S)[E]); (D)[E] = (short)cvt_bf16(f_ * f_); }
    SQE(s0, c0, 0) SQE(s0, c0, 1) SQE(s0, c0, 2) SQE(s0, c0, 3)
    SQE(s0, c0, 4) SQE(s0, c0, 5) SQE(s0, c0, 6) SQE(s0, c0, 7)
    SQE(s1, c1, 0) SQE(s1, c1, 1) SQE(s1, c1, 2) SQE(s1, c1, 3)
    SQE(s1, c1, 4) SQE(s1, c1, 5) SQE(s1, c1, 6) SQE(s1, c1, 7)
#undef SQE
    *reinterpret_cast<short8*>(&sH[0][sidx0]) = c0;
    *reinterpret_cast<short8*>(&sH[0][sidx1]) = c1;
    *reinterpret_cast<short8*>(&sH[1][sidx0]) = s0;
    *reinterpret_cast<short8*>(&sH[1][sidx1]) = s1;
    __syncthreads();

    const short8 bm = *reinterpret_cast<const short8*>(&w2p[boff + s * 32]);
    const short8 bv = *reinterpret_cast<const short8*>(&w2p[W2SQ + boff + s * 32]);
    const short8 af0 = *reinterpret_cast<const short8*>(&sH[0][aidx0]);
    const short8 af1 = *reinterpret_cast<const short8*>(&sH[0][aidx1]);
    const short8 ag0 = *reinterpret_cast<const short8*>(&sH[1][aidx0]);
    const short8 ag1 = *reinterpret_cast<const short8*>(&sH[1][aidx1]);
    am0 = __builtin_amdgcn_mfma_f32_16x16x32_bf16(af0, bm, am0, 0, 0, 0);
    av0 = __builtin_amdgcn_mfma_f32_16x16x32_bf16(ag0, bv, av0, 0, 0, 0);
    am1 = __builtin_amdgcn_mfma_f32_16x16x32_bf16(af1, bm, am1, 0, 0, 0);
    av1 = __builtin_amdgcn_mfma_f32_16x16x32_bf16(ag1, bv, av1, 0, 0, 0);
  }

  // epilogue: C/D layout col=l15, row=(lane>>4)*4+g; only cols 0..9 exist
  const float INV = 0.031622776601683794f;
  if (l15 < N_OUT) {
#define L2E(I, G) do { \
    const int row_ = gr0 + wv * 32 + I * 16 + lhal * 4 + (G); \
    float mean_ = 0.5f * am##I[G]; \
    float sd_ = 0.5f * sqrtf(av##I[G]); \
    float eps_ = eps_part(k2a, k2b, (uint32_t)row_ * 10u + (uint32_t)l15); \
    out[(size_t)row_ * 10 + l15] = mean_ + sd_ * (eps_ * INV); \
  } while (0)
    L2E(0, 0); L2E(0, 1); L2E(0, 2); L2E(0, 3);
    L2E(1, 0); L2E(1, 1); L2E(1, 2); L2E(1, 3);
#undef L2E
  }
}

extern "C" void kernel_launch(void* const* d_in, const int* in_sizes, int n_in,
                              void* d_out, int out_size, void* d_ws, size_t ws_size,
                              hipStream_t stream) {
  const float* x = (const float*)d_in[0];
  const float* W1 = (const float*)d_in[1];
  const float* W2 = (const float*)d_in[2];
  float* outp = (float*)d_out;
  u16* bp = (u16*)d_ws;                           // 819200 B
  u16* w2p = (u16*)((char*)d_ws + W2_OFF);        // 16 KB
  u16* hws = (u16*)((char*)d_ws + H_OFF);         // 33.5 MB

  // k1, k2 = jax.random.split(jax.random.key(42)), partitionable threefry
  uint32_t k1a, k1b, k2a, k2b;
  threefry2x32(0u, 42u, 0u, 0u, k1a, k1b);
  threefry2x32(0u, 42u, 0u, 1u, k2a, k2b);

  pack_w1<<<256, 256, 0, stream>>>(W1, bp);
  pack_w2<<<1, 256, 0, stream>>>(W2, w2p);
  gemm1<<<2048, 256, 0, stream>>>(x, bp, hws, k1a, k1b);
  layer2<<<65536 / BM2, 256, 0, stream>>>(hws, w2p, outp, k2a, k2b);
}